// Round 5
// baseline (89.954 us; speedup 1.0000x reference)
//
#include <hip/hip_runtime.h>
#include <cstdint>

#define M_TOT 8192
#define K_PTS 32
#define NCH 64
#define MT 16   // m per block; 4 per wave

typedef float f4 __attribute__((ext_vector_type(4)));

// score[k][j] (up to j-constant terms, which cancel in softmax) =
//   x_k.(A x_j) + u.x_j = (A^T x_k + u) . x_j,  A=(Wq^T Wk)*log2e/8, u=(Wk^T bq)*log2e/8
// sum_j attn = 1  =>  pe[k][c] = relu(Wv[c].y_k + bv[c]),  y_k = sum_j attn[k][j] x_j.
__global__ __launch_bounds__(256, 8) void attn_fused(const float* __restrict__ xyz,
                                                     const float* __restrict__ Wq,
                                                     const float* __restrict__ bq,
                                                     const float* __restrict__ Wk,
                                                     const float* __restrict__ Wv,
                                                     const float* __restrict__ bv,
                                                     float* __restrict__ out) {
  // x4: [m][k] float4 (x0,x1,x2,pad), row stride 132 floats -> staggered banks
  __shared__ __align__(16) float x4[MT * 132 + 4];
  // y: per-wave private region: [w][mp][half][k] float4
  __shared__ __align__(16) float ylds[4 * 512];

  const int t    = threadIdx.x;
  const int w    = t >> 6;
  const int lane = t & 63;
  const int b    = blockIdx.x >> 9;            // grid = 4 * 512
  const int m0   = (blockIdx.x & 511) * MT;

  const float* xb = xyz + ((size_t)b * 3 * K_PTS) * M_TOT + m0;

  // ---- issue staged x loads: 6 per thread, 64B coalesced runs (indices recomputed later)
  float xv[6];
  #pragma unroll
  for (int p = 0; p < 6; ++p) {
    int i = t + p * 256;
    xv[p] = xb[(size_t)(i >> 4) * M_TOT + (i & 15)];
  }

  // ---- per-wave butterfly: A = Wq^T Wk, u = Wk^T bq (redundant across waves)
  {
    float wq0 = Wq[lane*3+0], wq1 = Wq[lane*3+1], wq2 = Wq[lane*3+2];
    float wk0 = Wk[lane*3+0], wk1 = Wk[lane*3+1], wk2 = Wk[lane*3+2];
    float bqo = bq[lane];
    float A00 = wq0*wk0, A01 = wq0*wk1, A02 = wq0*wk2;
    float A10 = wq1*wk0, A11 = wq1*wk1, A12 = wq1*wk2;
    float A20 = wq2*wk0, A21 = wq2*wk1, A22 = wq2*wk2;
    float u0 = bqo*wk0, u1 = bqo*wk1, u2 = bqo*wk2;
    #pragma unroll
    for (int st = 1; st < 64; st <<= 1) {
      A00 += __shfl_xor(A00, st); A01 += __shfl_xor(A01, st); A02 += __shfl_xor(A02, st);
      A10 += __shfl_xor(A10, st); A11 += __shfl_xor(A11, st); A12 += __shfl_xor(A12, st);
      A20 += __shfl_xor(A20, st); A21 += __shfl_xor(A21, st); A22 += __shfl_xor(A22, st);
      u0  += __shfl_xor(u0,  st); u1  += __shfl_xor(u1,  st); u2  += __shfl_xor(u2,  st);
    }
    const float sc = 1.4426950408889634f / 8.0f; // log2(e)/sqrt(CH)
    A00 *= sc; A01 *= sc; A02 *= sc; A10 *= sc; A11 *= sc; A12 *= sc;
    A20 *= sc; A21 *= sc; A22 *= sc; u0 *= sc; u1 *= sc; u2 *= sc;

    // ---- stash x into LDS (recompute indices; 2-way max bank aliasing)
    #pragma unroll
    for (int p = 0; p < 6; ++p) {
      int i = t + p * 256;
      int r = i >> 4;                       // r = c*32 + k
      x4[(i & 15) * 132 + (r & 31) * 4 + (r >> 5)] = xv[p];
    }
    __syncthreads();   // the ONLY block barrier

    // ---- both m-pairs' w_k = A^T x_k + u now, so A/u die here
    const int half = lane >> 5;
    const int k    = lane & 31;
    #pragma unroll
    for (int mp = 0; mp < 2; ++mp) {
      const int mloc = w * 4 + mp * 2 + half;
      f4 xk = *(const f4*)&x4[mloc * 132 + k * 4];
      // reuse wq* as per-mp score vectors (saved via scope trickery below)
      float r0 = fmaf(A00, xk.x, fmaf(A10, xk.y, fmaf(A20, xk.z, u0)));
      float r1 = fmaf(A01, xk.x, fmaf(A11, xk.y, fmaf(A21, xk.z, u1)));
      float r2 = fmaf(A02, xk.x, fmaf(A12, xk.y, fmaf(A22, xk.z, u2)));
      // store into ylds temporarily? no — keep in regs via arrays
      if (mp == 0) { wq0 = r0; wq1 = r1; wq2 = r2; }
      else         { wk0 = r0; wk1 = r1; wk2 = r2; }
    }
    // fallthrough: wq0..2 = w_k(mp0), wk0..2 = w_k(mp1)

    // ---- Wv rows for this lane's 4 channels (L2-hot; latency hides under softmax)
    const int c4 = (lane & 15) * 4;
    f4 wva = *(const f4*)(Wv + c4 * 3);
    f4 wvb = *(const f4*)(Wv + c4 * 3 + 4);
    f4 wvc = *(const f4*)(Wv + c4 * 3 + 8);
    f4 bvv = *(const f4*)(bv + c4);

    #pragma unroll
    for (int mp = 0; mp < 2; ++mp) {
      const int mloc = w * 4 + mp * 2 + half;
      float wk0r = mp ? wk0 : wq0;
      float wk1r = mp ? wk1 : wq1;
      float wk2r = mp ? wk2 : wq2;

      float sum = 0.f, y0 = 0.f, y1 = 0.f, y2 = 0.f;
      #pragma unroll
      for (int j = 0; j < 32; ++j) {
        f4 xj = *(const f4*)&x4[mloc * 132 + j * 4];   // broadcast per half-wave
        float s = fmaf(wk0r, xj.x, fmaf(wk1r, xj.y, wk2r * xj.z));
        float p = exp2f(s);                             // |s| <~ 40: safe in fp32, ratios exact
        sum += p;
        y0 = fmaf(p, xj.x, y0);
        y1 = fmaf(p, xj.y, y1);
        y2 = fmaf(p, xj.z, y2);
      }
      float inv = 1.0f / sum;

      float* yw = &ylds[w * 512 + mp * 256];
      *(f4*)&yw[(half * 32 + k) * 4] = (f4){y0 * inv, y1 * inv, y2 * inv, 0.f};
      // within-wave LDS RAW across lanes: drain DS queue before cross-lane reads
      __asm__ volatile("s_waitcnt lgkmcnt(0)" ::: "memory");

      // ---- store this m-pair: 16 iterations x 1KB contiguous per wave-instr
      float* op = out + (((size_t)b * M_TOT + m0 + w * 4 + mp * 2) * K_PTS) * NCH;
      #pragma unroll
      for (int it = 0; it < 16; ++it) {
        int msel = it >> 3;
        int kk   = (it & 7) * 4 + (lane >> 4);
        f4 y = *(const f4*)&yw[(msel * 32 + kk) * 4];
        f4 r;
        r.x = fmaxf(0.f, fmaf(wva.x, y.x, fmaf(wva.y, y.y, fmaf(wva.z, y.z, bvv.x))));
        r.y = fmaxf(0.f, fmaf(wva.w, y.x, fmaf(wvb.x, y.y, fmaf(wvb.y, y.z, bvv.y))));
        r.z = fmaxf(0.f, fmaf(wvb.z, y.x, fmaf(wvb.w, y.y, fmaf(wvc.x, y.z, bvv.z))));
        r.w = fmaxf(0.f, fmaf(wvc.y, y.x, fmaf(wvc.z, y.y, fmaf(wvc.w, y.z, bvv.w))));
        __builtin_nontemporal_store(r, (f4*)(op + ((size_t)(msel * K_PTS + kk)) * NCH + c4));
      }
    }
  }
}

extern "C" void kernel_launch(void* const* d_in, const int* in_sizes, int n_in,
                              void* d_out, int out_size, void* d_ws, size_t ws_size,
                              hipStream_t stream) {
  const float* xyz = (const float*)d_in[0];
  const float* Wq  = (const float*)d_in[1];
  const float* bq  = (const float*)d_in[2];
  const float* Wk  = (const float*)d_in[3];
  // d_in[4] = bk: constant in j, cancels in softmax — unused
  const float* Wv  = (const float*)d_in[5];
  const float* bv  = (const float*)d_in[6];
  float* out = (float*)d_out;

  attn_fused<<<2048, 256, 0, stream>>>(xyz, Wq, bq, Wk, Wv, bv, out);
}

// Round 6
// 51.991 us; speedup vs baseline: 1.7302x; 1.7302x over previous
//
#include <hip/hip_runtime.h>
#include <cstdint>

#define M_TOT 8192
#define K_PTS 32
#define NCH 64
#define MT 16   // m per block; 4 per wave

typedef float f4 __attribute__((ext_vector_type(4)));

// score[k][j] (up to j-constant terms, which cancel in softmax) =
//   x_k.(A x_j) + u.x_j = (A^T x_k + u) . x_j,  A=(Wq^T Wk)*log2e/8, u=(Wk^T bq)*log2e/8
// sum_j attn = 1  =>  pe[k][c] = relu(Wv[c].y_k + bv[c]),  y_k = sum_j attn[k][j] x_j.
__global__ __launch_bounds__(256) void attn_fused(const float* __restrict__ xyz,
                                                  const float* __restrict__ Wq,
                                                  const float* __restrict__ bq,
                                                  const float* __restrict__ Wk,
                                                  const float* __restrict__ Wv,
                                                  const float* __restrict__ bv,
                                                  float* __restrict__ out) {
  // x4: [m][k] float4 (x0,x1,x2,pad), row stride 132 floats (33 f4) -> staggered banks
  __shared__ __align__(16) float x4[MT * 132 + 4];
  // y: per-wave, per-mpair private region: [w][mp][half][k] float4
  __shared__ __align__(16) float ylds[4 * 512];

  const int t    = threadIdx.x;
  const int w    = t >> 6;
  const int lane = t & 63;
  const int b    = blockIdx.x >> 9;            // grid = 4 * 512
  const int m0   = (blockIdx.x & 511) * MT;

  const float* xb = xyz + ((size_t)b * 3 * K_PTS) * M_TOT + m0;

  // ---- issue staged x loads: 6 per thread, 64B coalesced runs
  float xv[6]; int rr[6], mm[6];
  #pragma unroll
  for (int p = 0; p < 6; ++p) {
    int i = t + p * 256;
    mm[p] = i & 15;
    rr[p] = i >> 4;            // r = c*32 + k, 0..95
    xv[p] = xb[(size_t)rr[p] * M_TOT + mm[p]];
  }

  // ---- Wv rows for this lane's 4 channels (c4*3 floats is 16B aligned: 48B stride)
  const int c4 = (lane & 15) * 4;
  f4 wva = *(const f4*)(Wv + c4 * 3);
  f4 wvb = *(const f4*)(Wv + c4 * 3 + 4);
  f4 wvc = *(const f4*)(Wv + c4 * 3 + 8);
  f4 bvv = *(const f4*)(bv + c4);

  // ---- per-wave butterfly: A = Wq^T Wk, u = Wk^T bq (redundant across waves)
  const int o = lane;
  float wq0 = Wq[o*3+0], wq1 = Wq[o*3+1], wq2 = Wq[o*3+2];
  float wk0 = Wk[o*3+0], wk1 = Wk[o*3+1], wk2 = Wk[o*3+2];
  float bqo = bq[o];
  float A00 = wq0*wk0, A01 = wq0*wk1, A02 = wq0*wk2;
  float A10 = wq1*wk0, A11 = wq1*wk1, A12 = wq1*wk2;
  float A20 = wq2*wk0, A21 = wq2*wk1, A22 = wq2*wk2;
  float u0 = bqo*wk0, u1 = bqo*wk1, u2 = bqo*wk2;
  #pragma unroll
  for (int st = 1; st < 64; st <<= 1) {
    A00 += __shfl_xor(A00, st); A01 += __shfl_xor(A01, st); A02 += __shfl_xor(A02, st);
    A10 += __shfl_xor(A10, st); A11 += __shfl_xor(A11, st); A12 += __shfl_xor(A12, st);
    A20 += __shfl_xor(A20, st); A21 += __shfl_xor(A21, st); A22 += __shfl_xor(A22, st);
    u0  += __shfl_xor(u0,  st); u1  += __shfl_xor(u1,  st); u2  += __shfl_xor(u2,  st);
  }
  const float sc = 1.4426950408889634f / 8.0f; // log2(e)/sqrt(CH)
  A00 *= sc; A01 *= sc; A02 *= sc; A10 *= sc; A11 *= sc; A12 *= sc;
  A20 *= sc; A21 *= sc; A22 *= sc; u0 *= sc; u1 *= sc; u2 *= sc;

  // ---- stash x into LDS (2-way max bank aliasing)
  #pragma unroll
  for (int p = 0; p < 6; ++p) {
    int k = rr[p] & 31, c = rr[p] >> 5;
    x4[mm[p] * 132 + k * 4 + c] = xv[p];
  }
  __syncthreads();   // the ONLY block barrier

  // ---- per wave, fully independent from here: 2 m-pairs
  #pragma unroll
  for (int mp = 0; mp < 2; ++mp) {
    const int half = lane >> 5;
    const int mloc = w * 4 + mp * 2 + half;
    const int k    = lane & 31;

    f4 xk = *(const f4*)&x4[mloc * 132 + k * 4];
    // w_k = A^T x_k + u  (pre-scaled for exp2)
    float wk0r = fmaf(A00, xk.x, fmaf(A10, xk.y, fmaf(A20, xk.z, u0)));
    float wk1r = fmaf(A01, xk.x, fmaf(A11, xk.y, fmaf(A21, xk.z, u1)));
    float wk2r = fmaf(A02, xk.x, fmaf(A12, xk.y, fmaf(A22, xk.z, u2)));

    float sum = 0.f, y0 = 0.f, y1 = 0.f, y2 = 0.f;
    #pragma unroll
    for (int j = 0; j < 32; ++j) {
      f4 xj = *(const f4*)&x4[mloc * 132 + j * 4];   // broadcast per half-wave
      float s = fmaf(wk0r, xj.x, fmaf(wk1r, xj.y, wk2r * xj.z));
      float p = exp2f(s);                             // no max-sub: |s| <~ 40, safe in fp32
      sum += p;
      y0 = fmaf(p, xj.x, y0);
      y1 = fmaf(p, xj.y, y1);
      y2 = fmaf(p, xj.z, y2);
    }
    float inv = 1.0f / sum;

    float* yw = &ylds[w * 512 + mp * 256];
    *(f4*)&yw[(half * 32 + k) * 4] = (f4){y0 * inv, y1 * inv, y2 * inv, 0.f};
    // within-wave LDS RAW: drain DS queue (in-order per wave), keep compiler honest
    __asm__ volatile("s_waitcnt lgkmcnt(0)" ::: "memory");

    // ---- store this m-pair: 16 iterations x 1KB contiguous per wave-instr
    float* op = out + (((size_t)b * M_TOT + m0 + w * 4 + mp * 2) * K_PTS) * NCH;
    #pragma unroll
    for (int it = 0; it < 16; ++it) {
      int msel = it >> 3;
      int kk   = (it & 7) * 4 + (lane >> 4);
      f4 y = *(const f4*)&yw[(msel * 32 + kk) * 4];
      f4 r;
      r.x = fmaxf(0.f, fmaf(wva.x, y.x, fmaf(wva.y, y.y, fmaf(wva.z, y.z, bvv.x))));
      r.y = fmaxf(0.f, fmaf(wva.w, y.x, fmaf(wvb.x, y.y, fmaf(wvb.y, y.z, bvv.y))));
      r.z = fmaxf(0.f, fmaf(wvb.z, y.x, fmaf(wvb.w, y.y, fmaf(wvc.x, y.z, bvv.z))));
      r.w = fmaxf(0.f, fmaf(wvc.y, y.x, fmaf(wvc.z, y.y, fmaf(wvc.w, y.z, bvv.w))));
      __builtin_nontemporal_store(r, (f4*)(op + ((size_t)(msel * K_PTS + kk)) * NCH + c4));
    }
  }
}

extern "C" void kernel_launch(void* const* d_in, const int* in_sizes, int n_in,
                              void* d_out, int out_size, void* d_ws, size_t ws_size,
                              hipStream_t stream) {
  const float* xyz = (const float*)d_in[0];
  const float* Wq  = (const float*)d_in[1];
  const float* bq  = (const float*)d_in[2];
  const float* Wk  = (const float*)d_in[3];
  // d_in[4] = bk: constant in j, cancels in softmax — unused
  const float* Wv  = (const float*)d_in[5];
  const float* bv  = (const float*)d_in[6];
  float* out = (float*)d_out;

  attn_fused<<<2048, 256, 0, stream>>>(xyz, Wq, bq, Wk, Wv, bv, out);
}

// Round 7
// 49.422 us; speedup vs baseline: 1.8201x; 1.0520x over previous
//
#include <hip/hip_runtime.h>
#include <cstdint>

#define M_TOT 8192
#define K_PTS 32
#define NCH 64
#define MT 16   // m per block; 4 per wave

typedef float f4 __attribute__((ext_vector_type(4)));

// score[k][j] (up to j-constant terms, which cancel in softmax) =
//   x_k.(A x_j) + u.x_j = (A^T x_k + u) . x_j,  A=(Wq^T Wk)*log2e/8, u=(Wk^T bq)*log2e/8
// sum_j attn = 1  =>  pe[k][c] = relu(Wv[c].y_k + bv[c]),  y_k = sum_j attn[k][j] x_j.
__global__ __launch_bounds__(256) void attn_fused(const float* __restrict__ xyz,
                                                  const float* __restrict__ Wq,
                                                  const float* __restrict__ bq,
                                                  const float* __restrict__ Wk,
                                                  const float* __restrict__ Wv,
                                                  const float* __restrict__ bv,
                                                  float* __restrict__ out) {
  // x4: [m][k] float4 (x0,x1,x2,pad), row stride 132 floats (33 f4) -> staggered banks
  __shared__ __align__(16) float x4[MT * 132 + 4];
  // y: per-wave, per-mpair private region: [w][mp][half][k] float4
  __shared__ __align__(16) float ylds[4 * 512];

  const int t    = threadIdx.x;
  const int w    = t >> 6;
  const int lane = t & 63;
  const int b    = blockIdx.x >> 9;            // grid = 4 * 512
  const int m0   = (blockIdx.x & 511) * MT;

  const float* xb = xyz + ((size_t)b * 3 * K_PTS) * M_TOT + m0;

  // ---- issue staged x loads: 6 per thread, 64B coalesced runs (indices recomputed later)
  float xv[6];
  #pragma unroll
  for (int p = 0; p < 6; ++p) {
    int i = t + p * 256;
    xv[p] = xb[(size_t)(i >> 4) * M_TOT + (i & 15)];
  }

  // ---- per-wave butterfly: A = Wq^T Wk, u = Wk^T bq (redundant across waves)
  const int o = lane;
  float wq0 = Wq[o*3+0], wq1 = Wq[o*3+1], wq2 = Wq[o*3+2];
  float wk0 = Wk[o*3+0], wk1 = Wk[o*3+1], wk2 = Wk[o*3+2];
  float bqo = bq[o];
  float A00 = wq0*wk0, A01 = wq0*wk1, A02 = wq0*wk2;
  float A10 = wq1*wk0, A11 = wq1*wk1, A12 = wq1*wk2;
  float A20 = wq2*wk0, A21 = wq2*wk1, A22 = wq2*wk2;
  float u0 = bqo*wk0, u1 = bqo*wk1, u2 = bqo*wk2;
  #pragma unroll
  for (int st = 1; st < 64; st <<= 1) {
    A00 += __shfl_xor(A00, st); A01 += __shfl_xor(A01, st); A02 += __shfl_xor(A02, st);
    A10 += __shfl_xor(A10, st); A11 += __shfl_xor(A11, st); A12 += __shfl_xor(A12, st);
    A20 += __shfl_xor(A20, st); A21 += __shfl_xor(A21, st); A22 += __shfl_xor(A22, st);
    u0  += __shfl_xor(u0,  st); u1  += __shfl_xor(u1,  st); u2  += __shfl_xor(u2,  st);
  }
  const float sc = 1.4426950408889634f / 8.0f; // log2(e)/sqrt(CH)
  A00 *= sc; A01 *= sc; A02 *= sc; A10 *= sc; A11 *= sc; A12 *= sc;
  A20 *= sc; A21 *= sc; A22 *= sc; u0 *= sc; u1 *= sc; u2 *= sc;

  // ---- stash x into LDS (recompute indices; 2-way max bank aliasing)
  #pragma unroll
  for (int p = 0; p < 6; ++p) {
    int i = t + p * 256;
    int r = i >> 4;                       // r = c*32 + k
    x4[(i & 15) * 132 + (r & 31) * 4 + (r >> 5)] = xv[p];
  }
  __syncthreads();   // the ONLY block barrier

  // ---- Wv rows for this lane's 4 channels (issued after barrier; latency hides
  //      under the first softmax loop, and the 16 regs don't live through prologue)
  const int c4 = (lane & 15) * 4;
  f4 wva = *(const f4*)(Wv + c4 * 3);
  f4 wvb = *(const f4*)(Wv + c4 * 3 + 4);
  f4 wvc = *(const f4*)(Wv + c4 * 3 + 8);
  f4 bvv = *(const f4*)(bv + c4);

  // ---- per wave, fully independent from here: 2 m-pairs
  #pragma unroll
  for (int mp = 0; mp < 2; ++mp) {
    const int half = lane >> 5;
    const int mloc = w * 4 + mp * 2 + half;
    const int k    = lane & 31;

    f4 xk = *(const f4*)&x4[mloc * 132 + k * 4];
    // w_k = A^T x_k + u  (pre-scaled for exp2)
    float wk0r = fmaf(A00, xk.x, fmaf(A10, xk.y, fmaf(A20, xk.z, u0)));
    float wk1r = fmaf(A01, xk.x, fmaf(A11, xk.y, fmaf(A21, xk.z, u1)));
    float wk2r = fmaf(A02, xk.x, fmaf(A12, xk.y, fmaf(A22, xk.z, u2)));

    float sum = 0.f, y0 = 0.f, y1 = 0.f, y2 = 0.f;
    #pragma unroll
    for (int j = 0; j < 32; ++j) {
      f4 xj = *(const f4*)&x4[mloc * 132 + j * 4];   // broadcast per half-wave
      float s = fmaf(wk0r, xj.x, fmaf(wk1r, xj.y, wk2r * xj.z));
      float p = exp2f(s);                             // |s| <~ 40: safe in fp32, ratios exact
      sum += p;
      y0 = fmaf(p, xj.x, y0);
      y1 = fmaf(p, xj.y, y1);
      y2 = fmaf(p, xj.z, y2);
    }
    float inv = 1.0f / sum;

    float* yw = &ylds[w * 512 + mp * 256];
    *(f4*)&yw[(half * 32 + k) * 4] = (f4){y0 * inv, y1 * inv, y2 * inv, 0.f};
    // within-wave LDS RAW: drain DS queue (in-order per wave), keep compiler honest
    __asm__ volatile("s_waitcnt lgkmcnt(0)" ::: "memory");

    // ---- store this m-pair: 16 iterations x 1KB contiguous per wave-instr
    float* op = out + (((size_t)b * M_TOT + m0 + w * 4 + mp * 2) * K_PTS) * NCH;
    #pragma unroll
    for (int it = 0; it < 16; ++it) {
      int msel = it >> 3;
      int kk   = (it & 7) * 4 + (lane >> 4);
      f4 y = *(const f4*)&yw[(msel * 32 + kk) * 4];
      f4 r;
      r.x = fmaxf(0.f, fmaf(wva.x, y.x, fmaf(wva.y, y.y, fmaf(wva.z, y.z, bvv.x))));
      r.y = fmaxf(0.f, fmaf(wva.w, y.x, fmaf(wvb.x, y.y, fmaf(wvb.y, y.z, bvv.y))));
      r.z = fmaxf(0.f, fmaf(wvb.z, y.x, fmaf(wvb.w, y.y, fmaf(wvc.x, y.z, bvv.z))));
      r.w = fmaxf(0.f, fmaf(wvc.y, y.x, fmaf(wvc.z, y.y, fmaf(wvc.w, y.z, bvv.w))));
      *(f4*)(op + ((size_t)(msel * K_PTS + kk)) * NCH + c4) = r;
    }
  }
}

extern "C" void kernel_launch(void* const* d_in, const int* in_sizes, int n_in,
                              void* d_out, int out_size, void* d_ws, size_t ws_size,
                              hipStream_t stream) {
  const float* xyz = (const float*)d_in[0];
  const float* Wq  = (const float*)d_in[1];
  const float* bq  = (const float*)d_in[2];
  const float* Wk  = (const float*)d_in[3];
  // d_in[4] = bk: constant in j, cancels in softmax — unused
  const float* Wv  = (const float*)d_in[5];
  const float* bv  = (const float*)d_in[6];
  float* out = (float*)d_out;

  attn_fused<<<2048, 256, 0, stream>>>(xyz, Wq, bq, Wk, Wv, bv, out);
}